// Round 10
// baseline (79.362 us; speedup 1.0000x reference)
//
#include <hip/hip_runtime.h>
#include <hip/hip_bf16.h>

// LiftedStructureLoss on MI355X (gfx950)
// N=8192, D=128 fp32 embeddings; int labels (0..99); scalar fp32 out.
//
// 3 launches:
//   setup:  blocks 0..255 = prep (sq, bf16, zero sum_exp); block 256 = bucket
//   pass1:  STRIPS of 2 upper-triangle 128x128 tiles per block (A staged once,
//           B per tile, next-B issued under epilogue); exp(-d) sums over
//           negatives -> unsafeAtomicAdd(sum_exp)
//   pass2:  per-label within-label Gram (~1% of pairs) -> loss + n_pos;
//           ticket: last block reduces partials -> out
//
// exp(1-d) = e * exp(-d): the e is folded into pass2's sum_exp reads.

typedef __attribute__((ext_vector_type(8))) short bf16x8;
typedef __attribute__((ext_vector_type(4))) float f32x4;

__device__ __forceinline__ unsigned short f2bf(float f) {
    unsigned u = __float_as_uint(f);
    u += 0x7fffu + ((u >> 16) & 1u);   // round-to-nearest-even
    return (unsigned short)(u >> 16);
}

// Blocks 0..nPrep-1: prep 32 rows each (4 waves x 8 rows) + zero sum_exp.
// Block nPrep: bucket labels (256 threads).
__global__ __launch_bounds__(256) void setup_kernel(
    const float* __restrict__ e, const int* __restrict__ labels,
    float* __restrict__ sq, unsigned* __restrict__ ebf,
    float* __restrict__ sum_exp,
    int* __restrict__ counts_out, int* __restrict__ offsets_out,
    int* __restrict__ idxbuf, unsigned* __restrict__ ticket, int N)
{
    const int tid = threadIdx.x;
    if ((int)blockIdx.x < (int)gridDim.x - 1) {
        const int lane = tid & 63, wid = tid >> 6;
        if (tid < 32) sum_exp[blockIdx.x * 32 + tid] = 0.f;
        const int rowbase = (blockIdx.x * 4 + wid) * 8;
        #pragma unroll
        for (int it = 0; it < 8; ++it) {
            int row = rowbase + it;
            if (row >= N) break;
            float2 v = ((const float2*)(e + (size_t)row * 128))[lane];
            float s = v.x * v.x + v.y * v.y;
            #pragma unroll
            for (int off = 1; off < 64; off <<= 1) s += __shfl_xor(s, off, 64);
            if (lane == 0) sq[row] = s;
            unsigned bits = (unsigned)f2bf(v.x) | ((unsigned)f2bf(v.y) << 16);
            ebf[(size_t)row * 64 + lane] = bits;
        }
    } else {
        __shared__ int cnt[256];
        __shared__ int off[256];
        if (tid == 0) *ticket = 0u;
        cnt[tid] = 0;
        __syncthreads();
        for (int i = tid; i < N; i += 256)
            atomicAdd(&cnt[(unsigned)labels[i] & 255u], 1);
        __syncthreads();
        if (tid < 64) {
            int base = tid * 4;
            int c0 = cnt[base], c1 = cnt[base+1], c2 = cnt[base+2], c3 = cnt[base+3];
            int s = c0 + c1 + c2 + c3;
            int v = s;
            #pragma unroll
            for (int d = 1; d < 64; d <<= 1) {
                int u = __shfl_up(v, d, 64);
                if (tid >= d) v += u;
            }
            int excl = v - s;
            off[base]     = excl;
            off[base + 1] = excl + c0;
            off[base + 2] = excl + c0 + c1;
            off[base + 3] = excl + c0 + c1 + c2;
        }
        __syncthreads();
        counts_out[tid]  = cnt[tid];
        offsets_out[tid] = off[tid];
        cnt[tid] = off[tid];               // reuse as cursor
        __syncthreads();
        for (int i = tid; i < N; i += 256) {
            int l = (unsigned)labels[i] & 255u;
            int p = atomicAdd(&cnt[l], 1);
            idxbuf[p] = i;
        }
    }
}

// PASS 1: strips of up to 2 tiles in one block-row. 512 thr = 8 waves of
// 64x32 output. A-tile (full K=128, 32KB) staged once per strip; B staged
// per tile in 2 chunks of 16KB; next tile's B-chunk0 issued before the
// epilogue so its latency hides under ~3K cycles of VALU.
__global__ __launch_bounds__(512) void pass1_kernel(
    const unsigned short* __restrict__ ebf,
    const float* __restrict__ sq,
    const int* __restrict__ labels,
    float* __restrict__ sum_exp,       // accumulated via fp32 atomics
    int N, int nCb)
{
    __shared__ __align__(16) char a_tile[128 * 256];   // full-K A (32KB)
    __shared__ __align__(16) char b_tile[128 * 128];   // one B K-chunk (16KB)

    const int tid = threadIdx.x;
    const int lane = tid & 63, wid = tid >> 6;
    const int wm = (wid >> 2) * 64, wn = (wid & 3) * 32;
    const int lhi = lane >> 4, llo = lane & 15;
    const char* ebfB = (const char*)ebf;

    // ---- decode strip id -> (bi, bj0) ----
    {
    }
    int rem = blockIdx.x, bi = 0;
    while (true) {
        int c = (nCb - bi + 1) >> 1;        // strips in row bi
        if (rem < c) break;
        rem -= c; ++bi;
    }
    const int bj0 = bi + 2 * rem;
    const int nTiles = min(2, nCb - bj0);
    const int brow = bi * 128;

    // ---- prologue: stage A (full K) + B(bj0) chunk0 ----
    #pragma unroll
    for (int i = 0; i < 4; ++i) {          // A: 2048 slots, 4/thread
        int sl = tid + i * 512;
        int r = sl >> 4, j = sl & 15;
        const void* g = ebfB + ((size_t)(brow + r) << 8) + ((j ^ (r & 7)) << 4);
        char* l = a_tile + (size_t)(i * 512 + wid * 64) * 16 + lane * 16;
        __builtin_amdgcn_global_load_lds(
            (const __attribute__((address_space(1))) unsigned*)g,
            (__attribute__((address_space(3))) unsigned*)l, 16, 0, 0);
    }
    #pragma unroll
    for (int i = 0; i < 2; ++i) {          // B chunk0: 1024 slots, 2/thread
        int sl = tid + i * 512;
        int r = sl >> 3, j = sl & 7;
        const void* g = ebfB + ((size_t)(bj0 * 128 + r) << 8) + ((j ^ (r & 7)) << 4);
        char* l = b_tile + (size_t)(i * 512 + wid * 64) * 16 + lane * 16;
        __builtin_amdgcn_global_load_lds(
            (const __attribute__((address_space(1))) unsigned*)g,
            (__attribute__((address_space(3))) unsigned*)l, 16, 0, 0);
    }
    __syncthreads();   // drain

    // ---- per-strip row data (rows constant across tiles) ----
    float sqr[4][4]; int labr[4][4];
    #pragma unroll
    for (int m = 0; m < 4; ++m)
        #pragma unroll
        for (int r = 0; r < 4; ++r) {
            int row = brow + wm + m * 16 + lhi * 4 + r;
            sqr[m][r] = sq[row];
            labr[m][r] = labels[row];
        }
    float wsum[4][4] = {};                 // row partials, whole strip

    for (int u = 0; u < nTiles; ++u) {
        const int bj = bj0 + u;
        const int bcol = bj * 128;
        const bool diag = (bj == bi);

        f32x4 acc[4][2];
        #pragma unroll
        for (int m = 0; m < 4; ++m)
            #pragma unroll
            for (int n = 0; n < 2; ++n)
                acc[m][n] = (f32x4){0.f, 0.f, 0.f, 0.f};

        // ---- chunk 0 (k bytes 0..127) : b_tile ready ----
        #pragma unroll
        for (int h = 0; h < 2; ++h) {
            const int cba = h * 64 + lhi * 16;           // A col within chunk0
            const int cbb = h * 64 + lhi * 16;
            bf16x8 af[4], bfr[2];
            #pragma unroll
            for (int m = 0; m < 4; ++m) {
                int r = wm + m * 16 + llo;
                af[m] = *(const bf16x8*)(a_tile + r * 256 + (cba ^ ((r & 7) << 4)));
            }
            #pragma unroll
            for (int n = 0; n < 2; ++n) {
                int r = wn + n * 16 + llo;
                bfr[n] = *(const bf16x8*)(b_tile + r * 128 + (cbb ^ ((r & 7) << 4)));
            }
            #pragma unroll
            for (int m = 0; m < 4; ++m)
                #pragma unroll
                for (int n = 0; n < 2; ++n)
                    acc[m][n] = __builtin_amdgcn_mfma_f32_16x16x32_bf16(af[m], bfr[n], acc[m][n], 0, 0, 0);
        }
        __syncthreads();                     // b_tile reads done

        // stage B chunk1
        #pragma unroll
        for (int i = 0; i < 2; ++i) {
            int sl = tid + i * 512;
            int r = sl >> 3, j = sl & 7;
            const void* g = ebfB + ((size_t)(bcol + r) << 8) + 128 + ((j ^ (r & 7)) << 4);
            char* l = b_tile + (size_t)(i * 512 + wid * 64) * 16 + lane * 16;
            __builtin_amdgcn_global_load_lds(
                (const __attribute__((address_space(1))) unsigned*)g,
                (__attribute__((address_space(3))) unsigned*)l, 16, 0, 0);
        }
        __syncthreads();                     // drain (exposed ~L2 latency)

        // ---- chunk 1 (k bytes 128..255) ----
        #pragma unroll
        for (int h = 0; h < 2; ++h) {
            const int cba = 128 + h * 64 + lhi * 16;
            const int cbb = h * 64 + lhi * 16;
            bf16x8 af[4], bfr[2];
            #pragma unroll
            for (int m = 0; m < 4; ++m) {
                int r = wm + m * 16 + llo;
                af[m] = *(const bf16x8*)(a_tile + r * 256 + (cba ^ ((r & 7) << 4)));
            }
            #pragma unroll
            for (int n = 0; n < 2; ++n) {
                int r = wn + n * 16 + llo;
                bfr[n] = *(const bf16x8*)(b_tile + r * 128 + (cbb ^ ((r & 7) << 4)));
            }
            #pragma unroll
            for (int m = 0; m < 4; ++m)
                #pragma unroll
                for (int n = 0; n < 2; ++n)
                    acc[m][n] = __builtin_amdgcn_mfma_f32_16x16x32_bf16(af[m], bfr[n], acc[m][n], 0, 0, 0);
        }
        __syncthreads();                     // b_tile reads done

        // issue NEXT tile's B chunk0 (latency hides under epilogue)
        if (u + 1 < nTiles) {
            #pragma unroll
            for (int i = 0; i < 2; ++i) {
                int sl = tid + i * 512;
                int r = sl >> 3, j = sl & 7;
                const void* g = ebfB + ((size_t)(bcol + 128 + r) << 8) + ((j ^ (r & 7)) << 4);
                char* l = b_tile + (size_t)(i * 512 + wid * 64) * 16 + lane * 16;
                __builtin_amdgcn_global_load_lds(
                    (const __attribute__((address_space(1))) unsigned*)g,
                    (__attribute__((address_space(3))) unsigned*)l, 16, 0, 0);
            }
        }

        // ---- epilogue for tile bj ----
        float sqc[2]; int labc[2];
        #pragma unroll
        for (int n = 0; n < 2; ++n) {
            int col = bcol + wn + n * 16 + llo;
            sqc[n] = sq[col];
            labc[n] = labels[col];
        }
        float csum[2] = {};
        #pragma unroll
        for (int m = 0; m < 4; ++m)
            #pragma unroll
            for (int n = 0; n < 2; ++n)
                #pragma unroll
                for (int r = 0; r < 4; ++r) {
                    float g = acc[m][n][r];
                    float d2 = fmaxf(fmaf(-2.f, g, sqr[m][r] + sqc[n]), 0.f);
                    float dist = __builtin_amdgcn_sqrtf(d2);
                    float w = (labr[m][r] != labc[n]) ? __expf(-dist) : 0.f;
                    wsum[m][r] += w;
                    csum[n] += w;
                }
        if (!diag) {
            #pragma unroll
            for (int n = 0; n < 2; ++n) {
                float s = csum[n];
                s += __shfl_xor(s, 16, 64);
                s += __shfl_xor(s, 32, 64);
                if (lhi == 0)
                    unsafeAtomicAdd(&sum_exp[bcol + wn + n * 16 + llo], s);
            }
        }
        __syncthreads();                     // drain: next chunk0 ready
    }

    // ---- strip row-sum finalize ----
    #pragma unroll
    for (int m = 0; m < 4; ++m)
        #pragma unroll
        for (int r = 0; r < 4; ++r) {
            float s = wsum[m][r];
            #pragma unroll
            for (int off = 1; off < 16; off <<= 1) s += __shfl_xor(s, off, 64);
            if (llo == 0)
                unsafeAtomicAdd(&sum_exp[brow + wm + m * 16 + lhi * 4 + r], s);
        }
}

// PASS 2: one block per label; within-label Gram + loss (ordered counting).
// Last block (ticket) reduces partial2/cnt2 -> out.
__global__ __launch_bounds__(256) void pass2_kernel(
    const unsigned short* __restrict__ ebf,
    const float* __restrict__ sq,
    const float* __restrict__ sum_exp,
    const int* __restrict__ idxbuf,
    const int* __restrict__ offsets,
    const int* __restrict__ counts,
    double* __restrict__ partial2,
    unsigned* __restrict__ cnt2,
    unsigned* __restrict__ ticket,
    float* __restrict__ out)
{
    __shared__ __align__(16) char a_tile[128 * 128];
    __shared__ __align__(16) char b_tile[128 * 128];
    __shared__ double bsum[4];
    __shared__ unsigned bcnt[4];
    __shared__ bool isLast;

    const int L = blockIdx.x;
    const int NL = gridDim.x;
    const int tid = threadIdx.x;
    const int lane = tid & 63, wid = tid >> 6;
    const int cnt = counts[L], offs = offsets[L];
    const int wm = (wid >> 1) * 64, wn = (wid & 1) * 64;
    const int lhi = lane >> 4, llo = lane & 15;
    const char* ebfB = (const char*)ebf;
    const float E1 = 2.71828182845904523f;

    float lsum = 0.f; unsigned lcnt = 0;

    if (cnt > 1) {
        const int nSub = (cnt + 127) >> 7;
        for (int si = 0; si < nSub; ++si)
        for (int sj = si; sj < nSub; ++sj) {
            const int baseA = offs + si * 128, baseB = offs + sj * 128;
            const int cntA = min(128, cnt - si * 128);
            const int cntB = min(128, cnt - sj * 128);
            const float wgt = (si == sj) ? 1.f : 2.f;
            const unsigned wgtu = (si == sj) ? 1u : 2u;

            f32x4 acc[4][4];
            #pragma unroll
            for (int m = 0; m < 4; ++m)
                #pragma unroll
                for (int n = 0; n < 4; ++n)
                    acc[m][n] = (f32x4){0.f, 0.f, 0.f, 0.f};

            for (int c = 0; c < 2; ++c) {
                #pragma unroll
                for (int i2 = 0; i2 < 8; ++i2) {
                    int sl = tid + i2 * 256;
                    int tsel = sl >> 10;
                    int s = sl & 1023;
                    int r = s >> 3, j = s & 7;
                    int base = tsel ? baseB : baseA;
                    int cc = tsel ? cntB : cntA;
                    int gr = idxbuf[base + min(r, cc - 1)];
                    uint4 v = *(const uint4*)(ebfB + ((size_t)gr << 8) + c * 128 + (j << 4));
                    char* tp = tsel ? b_tile : a_tile;
                    *(uint4*)(tp + r * 128 + (((j << 4)) ^ ((r & 7) << 4))) = v;
                }
                __syncthreads();
                #pragma unroll
                for (int h = 0; h < 2; ++h) {
                    const int cb = h * 64 + lhi * 16;
                    bf16x8 af[4], bfr[4];
                    #pragma unroll
                    for (int m = 0; m < 4; ++m) {
                        int r = wm + m * 16 + llo;
                        af[m] = *(const bf16x8*)(a_tile + r * 128 + (cb ^ ((r & 7) << 4)));
                    }
                    #pragma unroll
                    for (int n = 0; n < 4; ++n) {
                        int r = wn + n * 16 + llo;
                        bfr[n] = *(const bf16x8*)(b_tile + r * 128 + (cb ^ ((r & 7) << 4)));
                    }
                    #pragma unroll
                    for (int m = 0; m < 4; ++m)
                        #pragma unroll
                        for (int n = 0; n < 4; ++n)
                            acc[m][n] = __builtin_amdgcn_mfma_f32_16x16x32_bf16(af[m], bfr[n], acc[m][n], 0, 0, 0);
                }
                __syncthreads();
            }

            int giA[4][4]; float sqA[4][4], seA[4][4]; bool vA[4][4];
            #pragma unroll
            for (int m = 0; m < 4; ++m)
                #pragma unroll
                for (int r = 0; r < 4; ++r) {
                    int lr = wm + m * 16 + lhi * 4 + r;
                    vA[m][r] = lr < cntA;
                    int gi = idxbuf[baseA + min(lr, cntA - 1)];
                    giA[m][r] = gi;
                    sqA[m][r] = sq[gi];
                    seA[m][r] = sum_exp[gi] * E1;
                }
            int gjB[4]; float sqB[4], seB[4]; bool vB[4];
            #pragma unroll
            for (int n = 0; n < 4; ++n) {
                int lc = wn + n * 16 + llo;
                vB[n] = lc < cntB;
                int gj = idxbuf[baseB + min(lc, cntB - 1)];
                gjB[n] = gj;
                sqB[n] = sq[gj];
                seB[n] = sum_exp[gj] * E1;
            }
            #pragma unroll
            for (int m = 0; m < 4; ++m)
                #pragma unroll
                for (int n = 0; n < 4; ++n)
                    #pragma unroll
                    for (int r = 0; r < 4; ++r) {
                        float g = acc[m][n][r];
                        float d2 = fmaxf(fmaf(-2.f, g, sqA[m][r] + sqB[n]), 0.f);
                        float dist = __builtin_amdgcn_sqrtf(d2);
                        bool pos = vA[m][r] && vB[n] && (giA[m][r] != gjB[n]);
                        float Lv = __logf(seA[m][r] + seB[n]) + dist;
                        Lv = fmaxf(Lv, 0.f);
                        lsum += pos ? wgt * Lv * Lv : 0.f;
                        lcnt += pos ? wgtu : 0u;
                    }
        }
    }

    #pragma unroll
    for (int off = 1; off < 64; off <<= 1) {
        lsum += __shfl_xor(lsum, off, 64);
        lcnt += __shfl_xor(lcnt, off, 64);
    }
    if (lane == 0) { bsum[wid] = (double)lsum; bcnt[wid] = lcnt; }
    __syncthreads();
    if (tid == 0) {
        partial2[L] = bsum[0] + bsum[1] + bsum[2] + bsum[3];
        cnt2[L] = bcnt[0] + bcnt[1] + bcnt[2] + bcnt[3];
        __threadfence();
        isLast = (atomicAdd(ticket, 1u) == (unsigned)(NL - 1));
    }
    __syncthreads();

    if (isLast) {
        __threadfence();
        double tt = (tid < NL) ? partial2[tid] : 0.0;
        unsigned c = (tid < NL) ? cnt2[tid] : 0u;
        #pragma unroll
        for (int off = 1; off < 64; off <<= 1) {
            tt += __shfl_xor(tt, off, 64);
            c  += __shfl_xor(c, off, 64);
        }
        if (lane == 0) { bsum[wid] = tt; bcnt[wid] = c; }
        __syncthreads();
        if (tid == 0) {
            double s = bsum[0] + bsum[1] + bsum[2] + bsum[3];
            unsigned cc = bcnt[0] + bcnt[1] + bcnt[2] + bcnt[3];
            if (cc == 0) cc = 1;
            out[0] = (float)(s / (double)cc * 0.5);
        }
    }
}

extern "C" void kernel_launch(void* const* d_in, const int* in_sizes, int n_in,
                              void* d_out, int out_size, void* d_ws, size_t ws_size,
                              hipStream_t stream) {
    const float* e = (const float*)d_in[0];
    const int* labels = (const int*)d_in[1];
    const int N = in_sizes[1];                 // 8192
    const int nCb = N / 128;                   // 64
    const int NL = 256;
    const int nPrep = N / 32;                  // 256

    // number of 2-tile strips: sum over bi of ceil((nCb-bi)/2)
    int nStrips = 0;
    for (int bi = 0; bi < nCb; ++bi) nStrips += (nCb - bi + 1) >> 1;   // 1056

    char* ws = (char*)d_ws;
    float*    sq       = (float*)ws;
    float*    sum_exp  = (float*)(ws + 4 * (size_t)N);
    unsigned short* ebf = (unsigned short*)(ws + 8 * (size_t)N);
    char*     p        = ws + 8 * (size_t)N + 256 * (size_t)N;
    int*      counts   = (int*)p;      p += NL * 4;
    int*      offsets  = (int*)p;      p += NL * 4;
    unsigned* ticket   = (unsigned*)p; p += 64;           // own cache line
    p = (char*)(((size_t)p + 7) & ~(size_t)7);
    double*   partial2 = (double*)p;   p += NL * 8;
    unsigned* cnt2     = (unsigned*)p; p += NL * 4;
    int*      idxbuf   = (int*)p;

    setup_kernel<<<nPrep + 1, 256, 0, stream>>>(e, labels, sq, (unsigned*)ebf,
                                                sum_exp, counts, offsets,
                                                idxbuf, ticket, N);
    pass1_kernel<<<nStrips, 512, 0, stream>>>(ebf, sq, labels, sum_exp, N, nCb);
    pass2_kernel<<<NL, 256, 0, stream>>>(ebf, sq, sum_exp, idxbuf, offsets, counts,
                                         partial2, cnt2, ticket, (float*)d_out);
}

// Round 11
// 73.014 us; speedup vs baseline: 1.0869x; 1.0869x over previous
//
#include <hip/hip_runtime.h>
#include <hip/hip_bf16.h>

// LiftedStructureLoss on MI355X (gfx950)
// N=8192, D=128 fp32 embeddings; int labels (0..99); scalar fp32 out.
//
// 3 launches:
//   setup:  blocks 0..255 = prep (sq, bf16, zero sum_exp); block 256 = bucket
//   pass1:  upper-triangle 128x128 tiles; SINGLE-STAGE full-K (A+B 64KB, one
//           drain barrier) -> 32 MFMA -> epilogue; exp(-d) sums over
//           negatives -> unsafeAtomicAdd(sum_exp)
//   pass2:  per-label within-label Gram (~1% of pairs) -> loss + n_pos;
//           ticket: last block reduces partials -> out
//
// exp(1-d) = e * exp(-d): the e is folded into pass2's sum_exp reads.

typedef __attribute__((ext_vector_type(8))) short bf16x8;
typedef __attribute__((ext_vector_type(4))) float f32x4;

__device__ __forceinline__ unsigned short f2bf(float f) {
    unsigned u = __float_as_uint(f);
    u += 0x7fffu + ((u >> 16) & 1u);   // round-to-nearest-even
    return (unsigned short)(u >> 16);
}

// Blocks 0..nPrep-1: prep 32 rows each (4 waves x 8 rows) + zero sum_exp.
// Block nPrep: bucket labels (256 threads).
__global__ __launch_bounds__(256) void setup_kernel(
    const float* __restrict__ e, const int* __restrict__ labels,
    float* __restrict__ sq, unsigned* __restrict__ ebf,
    float* __restrict__ sum_exp,
    int* __restrict__ counts_out, int* __restrict__ offsets_out,
    int* __restrict__ idxbuf, unsigned* __restrict__ ticket, int N)
{
    const int tid = threadIdx.x;
    if ((int)blockIdx.x < (int)gridDim.x - 1) {
        const int lane = tid & 63, wid = tid >> 6;
        if (tid < 32) sum_exp[blockIdx.x * 32 + tid] = 0.f;
        const int rowbase = (blockIdx.x * 4 + wid) * 8;
        #pragma unroll
        for (int it = 0; it < 8; ++it) {
            int row = rowbase + it;
            if (row >= N) break;
            float2 v = ((const float2*)(e + (size_t)row * 128))[lane];
            float s = v.x * v.x + v.y * v.y;
            #pragma unroll
            for (int off = 1; off < 64; off <<= 1) s += __shfl_xor(s, off, 64);
            if (lane == 0) sq[row] = s;
            unsigned bits = (unsigned)f2bf(v.x) | ((unsigned)f2bf(v.y) << 16);
            ebf[(size_t)row * 64 + lane] = bits;
        }
    } else {
        __shared__ int cnt[256];
        __shared__ int off[256];
        if (tid == 0) *ticket = 0u;
        cnt[tid] = 0;
        __syncthreads();
        for (int i = tid; i < N; i += 256)
            atomicAdd(&cnt[(unsigned)labels[i] & 255u], 1);
        __syncthreads();
        if (tid < 64) {
            int base = tid * 4;
            int c0 = cnt[base], c1 = cnt[base+1], c2 = cnt[base+2], c3 = cnt[base+3];
            int s = c0 + c1 + c2 + c3;
            int v = s;
            #pragma unroll
            for (int d = 1; d < 64; d <<= 1) {
                int u = __shfl_up(v, d, 64);
                if (tid >= d) v += u;
            }
            int excl = v - s;
            off[base]     = excl;
            off[base + 1] = excl + c0;
            off[base + 2] = excl + c0 + c1;
            off[base + 3] = excl + c0 + c1 + c2;
        }
        __syncthreads();
        counts_out[tid]  = cnt[tid];
        offsets_out[tid] = off[tid];
        cnt[tid] = off[tid];               // reuse as cursor
        __syncthreads();
        for (int i = tid; i < N; i += 256) {
            int l = (unsigned)labels[i] & 255u;
            int p = atomicAdd(&cnt[l], 1);
            idxbuf[p] = i;
        }
    }
}

// PASS 1: one 128x128 upper-triangle tile per block, 512 thr = 8 waves of
// 64x32 output. Full-K A+B staged in ONE volley (8 global_load_lds/thread),
// one drain barrier, 32 MFMA, epilogue, one final barrier. 66KB LDS ->
// 2 blocks/CU; cross-block MFMA/VALU/stage overlap hides the drains.
__global__ __launch_bounds__(512) void pass1_kernel(
    const unsigned short* __restrict__ ebf,
    const float* __restrict__ sq,
    const int* __restrict__ labels,
    float* __restrict__ sum_exp,       // accumulated via fp32 atomics
    int N, int nCb)
{
    __shared__ __align__(16) char a_tile[128 * 256];   // full-K A (32KB)
    __shared__ __align__(16) char b_tile[128 * 256];   // full-K B (32KB)
    __shared__ float rowsum[128];
    __shared__ float colsum[128];

    const int tid = threadIdx.x;
    const int lane = tid & 63, wid = tid >> 6;

    // decode linear tile id -> (bi, bj), bi <= bj
    const int t = blockIdx.x;
    int bi = (int)((2.f * nCb + 1.f - __builtin_amdgcn_sqrtf(
                   (2.f * nCb + 1.f) * (2.f * nCb + 1.f) - 8.f * t)) * 0.5f);
    if (bi < 0) bi = 0;
    if (bi > nCb - 1) bi = nCb - 1;
    while (bi + 1 <= nCb - 1 && (bi + 1) * (2 * nCb - bi) / 2 <= t) ++bi;
    while (bi > 0 && bi * (2 * nCb - bi + 1) / 2 > t) --bi;
    const int bj = bi + (t - bi * (2 * nCb - bi + 1) / 2);
    const bool diag = (bi == bj);
    const int brow = bi * 128, bcol = bj * 128;

    if (tid < 128) { rowsum[tid] = 0.f; colsum[tid] = 0.f; }

    const char* ebfB = (const char*)ebf;

    // ---- single stage volley: 4096 16B slots (A: 0..2047, B: 2048..4095).
    // wave wid covers [wid*512, wid*512+512); 16 slots per 256B row.
    #pragma unroll
    for (int k = 0; k < 8; ++k) {
        int s = wid * 512 + k * 64;          // wave-uniform slot base
        int tsel = s >> 11;                  // 0: a_tile, 1: b_tile
        int ls = s & 2047;
        int sl = ls + lane;                  // per-lane slot within tile
        int r = sl >> 4, j = sl & 15;
        int grow = (tsel ? bcol : brow) + r;
        const void* g = ebfB + ((size_t)grow << 8) + ((j ^ (r & 7)) << 4);
        char* l = (tsel ? b_tile : a_tile) + ls * 16;   // wave-uniform base
        __builtin_amdgcn_global_load_lds(
            (const __attribute__((address_space(1))) unsigned*)g,
            (__attribute__((address_space(3))) unsigned*)l, 16, 0, 0);
    }
    __syncthreads();   // one drain for the whole tile

    const int wm = (wid >> 2) * 64, wn = (wid & 3) * 32;
    const int lhi = lane >> 4, llo = lane & 15;

    f32x4 acc[4][2];
    #pragma unroll
    for (int m = 0; m < 4; ++m)
        #pragma unroll
        for (int n = 0; n < 2; ++n)
            acc[m][n] = (f32x4){0.f, 0.f, 0.f, 0.f};

    #pragma unroll
    for (int ks = 0; ks < 4; ++ks) {
        const int cb = ks * 64 + lhi * 16;
        bf16x8 af[4], bfr[2];
        #pragma unroll
        for (int m = 0; m < 4; ++m) {
            int r = wm + m * 16 + llo;
            af[m] = *(const bf16x8*)(a_tile + r * 256 + (cb ^ ((r & 7) << 4)));
        }
        #pragma unroll
        for (int n = 0; n < 2; ++n) {
            int r = wn + n * 16 + llo;
            bfr[n] = *(const bf16x8*)(b_tile + r * 256 + (cb ^ ((r & 7) << 4)));
        }
        #pragma unroll
        for (int m = 0; m < 4; ++m)
            #pragma unroll
            for (int n = 0; n < 2; ++n)
                acc[m][n] = __builtin_amdgcn_mfma_f32_16x16x32_bf16(af[m], bfr[n], acc[m][n], 0, 0, 0);
    }

    // ---- epilogue: masked exp sums ----
    // C/D layout: col = lane&15, row = (lane>>4)*4 + reg
    const int rowbase = brow + wm;
    float sqr[4][4]; int labr[4][4];
    #pragma unroll
    for (int m = 0; m < 4; ++m)
        #pragma unroll
        for (int r = 0; r < 4; ++r) {
            int row = rowbase + m * 16 + lhi * 4 + r;
            sqr[m][r] = sq[row];
            labr[m][r] = labels[row];
        }
    float sqc[2]; int labc[2];
    #pragma unroll
    for (int n = 0; n < 2; ++n) {
        int col = bcol + wn + n * 16 + llo;
        sqc[n] = sq[col];
        labc[n] = labels[col];
    }

    float wsum[4][4] = {};
    float csum[2] = {};
    #pragma unroll
    for (int m = 0; m < 4; ++m)
        #pragma unroll
        for (int n = 0; n < 2; ++n)
            #pragma unroll
            for (int r = 0; r < 4; ++r) {
                float g = acc[m][n][r];
                float d2 = fmaxf(fmaf(-2.f, g, sqr[m][r] + sqc[n]), 0.f);
                float dist = __builtin_amdgcn_sqrtf(d2);
                float w = (labr[m][r] != labc[n]) ? __expf(-dist) : 0.f;
                wsum[m][r] += w;
                csum[n] += w;
            }
    // row sums: reduce across 16 llo lanes, accumulate in LDS
    #pragma unroll
    for (int m = 0; m < 4; ++m)
        #pragma unroll
        for (int r = 0; r < 4; ++r) {
            float s = wsum[m][r];
            #pragma unroll
            for (int off = 1; off < 16; off <<= 1) s += __shfl_xor(s, off, 64);
            if (llo == 0)
                atomicAdd(&rowsum[wm + m * 16 + lhi * 4 + r], s);
        }
    // col sums: reduce across the 4 lhi groups
    if (!diag) {
        #pragma unroll
        for (int n = 0; n < 2; ++n) {
            float s = csum[n];
            s += __shfl_xor(s, 16, 64);
            s += __shfl_xor(s, 32, 64);
            if (lhi == 0)
                atomicAdd(&colsum[wn + n * 16 + llo], s);
        }
    }
    __syncthreads();
    if (tid < 128) {
        unsafeAtomicAdd(&sum_exp[brow + tid], rowsum[tid]);
        if (!diag)
            unsafeAtomicAdd(&sum_exp[bcol + tid], colsum[tid]);
    }
}

// PASS 2: one block per label; within-label Gram + loss (ordered counting).
// Last block (ticket) reduces partial2/cnt2 -> out.
__global__ __launch_bounds__(256) void pass2_kernel(
    const unsigned short* __restrict__ ebf,
    const float* __restrict__ sq,
    const float* __restrict__ sum_exp,
    const int* __restrict__ idxbuf,
    const int* __restrict__ offsets,
    const int* __restrict__ counts,
    double* __restrict__ partial2,
    unsigned* __restrict__ cnt2,
    unsigned* __restrict__ ticket,
    float* __restrict__ out)
{
    __shared__ __align__(16) char a_tile[128 * 128];
    __shared__ __align__(16) char b_tile[128 * 128];
    __shared__ double bsum[4];
    __shared__ unsigned bcnt[4];
    __shared__ bool isLast;

    const int L = blockIdx.x;
    const int NL = gridDim.x;
    const int tid = threadIdx.x;
    const int lane = tid & 63, wid = tid >> 6;
    const int cnt = counts[L], offs = offsets[L];
    const int wm = (wid >> 1) * 64, wn = (wid & 1) * 64;
    const int lhi = lane >> 4, llo = lane & 15;
    const char* ebfB = (const char*)ebf;
    const float E1 = 2.71828182845904523f;

    float lsum = 0.f; unsigned lcnt = 0;

    if (cnt > 1) {
        const int nSub = (cnt + 127) >> 7;
        for (int si = 0; si < nSub; ++si)
        for (int sj = si; sj < nSub; ++sj) {
            const int baseA = offs + si * 128, baseB = offs + sj * 128;
            const int cntA = min(128, cnt - si * 128);
            const int cntB = min(128, cnt - sj * 128);
            const float wgt = (si == sj) ? 1.f : 2.f;
            const unsigned wgtu = (si == sj) ? 1u : 2u;

            f32x4 acc[4][4];
            #pragma unroll
            for (int m = 0; m < 4; ++m)
                #pragma unroll
                for (int n = 0; n < 4; ++n)
                    acc[m][n] = (f32x4){0.f, 0.f, 0.f, 0.f};

            for (int c = 0; c < 2; ++c) {
                #pragma unroll
                for (int i2 = 0; i2 < 8; ++i2) {
                    int sl = tid + i2 * 256;
                    int tsel = sl >> 10;
                    int s = sl & 1023;
                    int r = s >> 3, j = s & 7;
                    int base = tsel ? baseB : baseA;
                    int cc = tsel ? cntB : cntA;
                    int gr = idxbuf[base + min(r, cc - 1)];
                    uint4 v = *(const uint4*)(ebfB + ((size_t)gr << 8) + c * 128 + (j << 4));
                    char* tp = tsel ? b_tile : a_tile;
                    *(uint4*)(tp + r * 128 + (((j << 4)) ^ ((r & 7) << 4))) = v;
                }
                __syncthreads();
                #pragma unroll
                for (int h = 0; h < 2; ++h) {
                    const int cb = h * 64 + lhi * 16;
                    bf16x8 af[4], bfr[4];
                    #pragma unroll
                    for (int m = 0; m < 4; ++m) {
                        int r = wm + m * 16 + llo;
                        af[m] = *(const bf16x8*)(a_tile + r * 128 + (cb ^ ((r & 7) << 4)));
                    }
                    #pragma unroll
                    for (int n = 0; n < 4; ++n) {
                        int r = wn + n * 16 + llo;
                        bfr[n] = *(const bf16x8*)(b_tile + r * 128 + (cb ^ ((r & 7) << 4)));
                    }
                    #pragma unroll
                    for (int m = 0; m < 4; ++m)
                        #pragma unroll
                        for (int n = 0; n < 4; ++n)
                            acc[m][n] = __builtin_amdgcn_mfma_f32_16x16x32_bf16(af[m], bfr[n], acc[m][n], 0, 0, 0);
                }
                __syncthreads();
            }

            int giA[4][4]; float sqA[4][4], seA[4][4]; bool vA[4][4];
            #pragma unroll
            for (int m = 0; m < 4; ++m)
                #pragma unroll
                for (int r = 0; r < 4; ++r) {
                    int lr = wm + m * 16 + lhi * 4 + r;
                    vA[m][r] = lr < cntA;
                    int gi = idxbuf[baseA + min(lr, cntA - 1)];
                    giA[m][r] = gi;
                    sqA[m][r] = sq[gi];
                    seA[m][r] = sum_exp[gi] * E1;
                }
            int gjB[4]; float sqB[4], seB[4]; bool vB[4];
            #pragma unroll
            for (int n = 0; n < 4; ++n) {
                int lc = wn + n * 16 + llo;
                vB[n] = lc < cntB;
                int gj = idxbuf[baseB + min(lc, cntB - 1)];
                gjB[n] = gj;
                sqB[n] = sq[gj];
                seB[n] = sum_exp[gj] * E1;
            }
            #pragma unroll
            for (int m = 0; m < 4; ++m)
                #pragma unroll
                for (int n = 0; n < 4; ++n)
                    #pragma unroll
                    for (int r = 0; r < 4; ++r) {
                        float g = acc[m][n][r];
                        float d2 = fmaxf(fmaf(-2.f, g, sqA[m][r] + sqB[n]), 0.f);
                        float dist = __builtin_amdgcn_sqrtf(d2);
                        bool pos = vA[m][r] && vB[n] && (giA[m][r] != gjB[n]);
                        float Lv = __logf(seA[m][r] + seB[n]) + dist;
                        Lv = fmaxf(Lv, 0.f);
                        lsum += pos ? wgt * Lv * Lv : 0.f;
                        lcnt += pos ? wgtu : 0u;
                    }
        }
    }

    #pragma unroll
    for (int off = 1; off < 64; off <<= 1) {
        lsum += __shfl_xor(lsum, off, 64);
        lcnt += __shfl_xor(lcnt, off, 64);
    }
    if (lane == 0) { bsum[wid] = (double)lsum; bcnt[wid] = lcnt; }
    __syncthreads();
    if (tid == 0) {
        partial2[L] = bsum[0] + bsum[1] + bsum[2] + bsum[3];
        cnt2[L] = bcnt[0] + bcnt[1] + bcnt[2] + bcnt[3];
        __threadfence();
        isLast = (atomicAdd(ticket, 1u) == (unsigned)(NL - 1));
    }
    __syncthreads();

    if (isLast) {
        __threadfence();
        double tt = (tid < NL) ? partial2[tid] : 0.0;
        unsigned c = (tid < NL) ? cnt2[tid] : 0u;
        #pragma unroll
        for (int off = 1; off < 64; off <<= 1) {
            tt += __shfl_xor(tt, off, 64);
            c  += __shfl_xor(c, off, 64);
        }
        if (lane == 0) { bsum[wid] = tt; bcnt[wid] = c; }
        __syncthreads();
        if (tid == 0) {
            double s = bsum[0] + bsum[1] + bsum[2] + bsum[3];
            unsigned cc = bcnt[0] + bcnt[1] + bcnt[2] + bcnt[3];
            if (cc == 0) cc = 1;
            out[0] = (float)(s / (double)cc * 0.5);
        }
    }
}

extern "C" void kernel_launch(void* const* d_in, const int* in_sizes, int n_in,
                              void* d_out, int out_size, void* d_ws, size_t ws_size,
                              hipStream_t stream) {
    const float* e = (const float*)d_in[0];
    const int* labels = (const int*)d_in[1];
    const int N = in_sizes[1];                 // 8192
    const int nCb = N / 128;                   // 64
    const int nT = nCb * (nCb + 1) / 2;        // 2080
    const int NL = 256;
    const int nPrep = N / 32;                  // 256

    char* ws = (char*)d_ws;
    float*    sq       = (float*)ws;
    float*    sum_exp  = (float*)(ws + 4 * (size_t)N);
    unsigned short* ebf = (unsigned short*)(ws + 8 * (size_t)N);
    char*     p        = ws + 8 * (size_t)N + 256 * (size_t)N;
    int*      counts   = (int*)p;      p += NL * 4;
    int*      offsets  = (int*)p;      p += NL * 4;
    unsigned* ticket   = (unsigned*)p; p += 64;           // own cache line
    p = (char*)(((size_t)p + 7) & ~(size_t)7);
    double*   partial2 = (double*)p;   p += NL * 8;
    unsigned* cnt2     = (unsigned*)p; p += NL * 4;
    int*      idxbuf   = (int*)p;

    setup_kernel<<<nPrep + 1, 256, 0, stream>>>(e, labels, sq, (unsigned*)ebf,
                                                sum_exp, counts, offsets,
                                                idxbuf, ticket, N);
    pass1_kernel<<<nT, 512, 0, stream>>>(ebf, sq, labels, sum_exp, N, nCb);
    pass2_kernel<<<NL, 256, 0, stream>>>(ebf, sq, sum_exp, idxbuf, offsets, counts,
                                         partial2, cnt2, ticket, (float*)d_out);
}